// Round 1
// baseline (158.916 us; speedup 1.0000x reference)
//
#include <hip/hip_runtime.h>

// BAD descriptor: direct per-radius box-mean maps + quad-gather main kernel.
// B=2, H=W=224, P=256, max_radius=3, radii in {1,2,3}.
#define BN 2
#define HN 224
#define WN 224
#define PN 256
#define NPIX (HN * WN)  // 50176

// Direct clamped (2r+1)^2-tap box sum. x is L1/L2-resident (200 KB/batch);
// every tap is a lane-contiguous wave-load.
template<int RAD>
__device__ __forceinline__ float box_sum(const float* __restrict__ xb, int y, int xc)
{
    int xs[2 * RAD + 1];
#pragma unroll
    for (int dx = -RAD; dx <= RAD; ++dx) {
        int xx = xc + dx;
        xs[dx + RAD] = xx < 0 ? 0 : (xx > WN - 1 ? WN - 1 : xx);
    }
    float s = 0.0f;
#pragma unroll
    for (int dy = -RAD; dy <= RAD; ++dy) {
        int yy = y + dy;
        yy = yy < 0 ? 0 : (yy > HN - 1 ? HN - 1 : yy);
        const float* row = xb + yy * WN;
#pragma unroll
        for (int k = 0; k < 2 * RAD + 1; ++k) s += row[xs[k]];
    }
    return s;
}

// BM[r-1][b][y][x] = mean of x[clamp(y+dy)][clamp(x+dx)], dy,dx in [-r,r].
// 6 maps x 200 KB = 1.2 MB in d_ws.
__global__ __launch_bounds__(256) void box_mean_direct_kernel(
    const float* __restrict__ x, float* __restrict__ BM)
{
    const int zb = blockIdx.z;                 // r_idx*2 + b
    const int r_idx = zb >> 1, b = zb & 1;
    const int xi = blockIdx.x * 64 + threadIdx.x;   // 0..255 (mask xi<224 on store)
    const int y  = blockIdx.y * 4 + threadIdx.y;
    const int xc = xi < WN ? xi : WN - 1;           // keep masked lanes in-bounds

    const float* xb = x + b * NPIX;
    float s;
    if (r_idx == 0)      s = box_sum<1>(xb, y, xc) * (1.0f / 9.0f);
    else if (r_idx == 1) s = box_sum<2>(xb, y, xc) * (1.0f / 25.0f);
    else                 s = box_sum<3>(xb, y, xc) * (1.0f / 49.0f);

    if (xi < WN)
        BM[(size_t)zb * NPIX + y * WN + xi] = s;
}

// Main v2: each lane owns a 4-column quad -> float4 (dwordx4) stores.
// out(b,p,y,x) = BM_r[b][cy1][cx1] - BM_r[b][cy2][cx2] - t.
// Block (64,4): wave = one row, lane covers x = 4*lane .. 4*lane+3 (lanes >=56
// masked on store). Grid (4, P, B): 56-row stripes. Per row-iteration:
//   - cy1/cy2 via wave-uniform clamp + readfirstlane -> scalar row base
//   - 8 gathers as SGPR-base + precomputed per-lane voffset (no per-load VALU)
//   - 1 aligned dwordx4 store (1 KB/wave-store)
// unroll 2 -> 16 loads in flight/wave, 8 waves/SIMD.
__global__ __launch_bounds__(256) void bad_main_kernel(
    const float* __restrict__ BM,
    const float* __restrict__ ox1, const float* __restrict__ ox2,
    const float* __restrict__ oy1, const float* __restrict__ oy2,
    const int*   __restrict__ radii, const float* __restrict__ thr,
    float* __restrict__ out)
{
    const int p    = blockIdx.y;
    const int b    = blockIdx.z;
    const int ys   = blockIdx.x;            // 0..3 -> 56-row stripe
    const int lane = threadIdx.x;           // 0..63
    const int wy   = threadIdx.y;           // 0..3, uniform per wave
    const int x0   = lane << 2;             // 0..252, valid when < 224

    // block-uniform descriptor params -> scalar loads
    const float offx1 = ox1[p], offx2 = ox2[p];
    const float offy1 = oy1[p], offy2 = oy2[p];
    const int   rad   = radii[p];
    const float t     = thr[p];

    const float* __restrict__ map = BM + (size_t)((rad - 1) * BN + b) * NPIX;

    // per-lane column indices for the 4-quad, computed once.
    // Bit-exact with reference: f32 add -> clamp -> trunc, per element.
    int vx1[4], vx2[4];
#pragma unroll
    for (int e = 0; e < 4; ++e) {
        const float fx = (float)(x0 + e);
        vx1[e] = (int)fminf(fmaxf(fx + offx1, 0.0f), (float)(WN - 1));
        vx2[e] = (int)fminf(fmaxf(fx + offx2, 0.0f), (float)(WN - 1));
    }

    const bool ok = (x0 < WN);              // lanes 56..63 compute but don't store
    const int  y0 = ys * (HN / 4) + wy;
    float* __restrict__ outp =
        out + (size_t)(b * PN + p) * NPIX + (size_t)y0 * WN + x0;

#pragma unroll 2
    for (int i = 0; i < HN / 4; i += 4) {
        const float fy = (float)(y0 + i);
        const int cy1 = __builtin_amdgcn_readfirstlane(
                            (int)fminf(fmaxf(fy + offy1, 0.0f), (float)(HN - 1)));
        const int cy2 = __builtin_amdgcn_readfirstlane(
                            (int)fminf(fmaxf(fy + offy2, 0.0f), (float)(HN - 1)));
        const float* __restrict__ r1 = map + cy1 * WN;   // scalar base
        const float* __restrict__ r2 = map + cy2 * WN;   // scalar base

        float4 v;
        v.x = r1[vx1[0]] - r2[vx2[0]] - t;
        v.y = r1[vx1[1]] - r2[vx2[1]] - t;
        v.z = r1[vx1[2]] - r2[vx2[2]] - t;
        v.w = r1[vx1[3]] - r2[vx2[3]] - t;

        if (ok)
            *reinterpret_cast<float4*>(outp + (size_t)i * WN) = v;
    }
}

extern "C" void kernel_launch(void* const* d_in, const int* in_sizes, int n_in,
                              void* d_out, int out_size, void* d_ws, size_t ws_size,
                              hipStream_t stream)
{
    const float* x    = (const float*)d_in[0];
    const float* ox1  = (const float*)d_in[1];
    const float* ox2  = (const float*)d_in[2];
    const float* oy1  = (const float*)d_in[3];
    const float* oy2  = (const float*)d_in[4];
    const int*   rad  = (const int*)d_in[5];
    const float* thr  = (const float*)d_in[6];

    float* BM  = (float*)d_ws;                // 6 * NPIX floats = ~1.2 MB
    float* out = (float*)d_out;

    hipLaunchKernelGGL(box_mean_direct_kernel, dim3(4, HN / 4, 6), dim3(64, 4, 1), 0, stream, x, BM);
    hipLaunchKernelGGL(bad_main_kernel,        dim3(4, PN, BN),    dim3(64, 4, 1), 0, stream,
                       BM, ox1, ox2, oy1, oy2, rad, thr, out);
}

// Round 2
// 134.523 us; speedup vs baseline: 1.1813x; 1.1813x over previous
//
#include <hip/hip_runtime.h>

// BAD descriptor: direct per-radius box-mean maps + row-streaming main kernel.
// B=2, H=W=224, P=256, max_radius=3, radii in {1,2,3}.
#define BN 2
#define HN 224
#define WN 224
#define PN 256
#define NPIX (HN * WN)  // 50176

// Direct clamped (2r+1)^2-tap box sum. x is L1/L2-resident (200 KB/batch);
// every tap is a lane-contiguous wave-load.
template<int RAD>
__device__ __forceinline__ float box_sum(const float* __restrict__ xb, int y, int xc)
{
    int xs[2 * RAD + 1];
#pragma unroll
    for (int dx = -RAD; dx <= RAD; ++dx) {
        int xx = xc + dx;
        xs[dx + RAD] = xx < 0 ? 0 : (xx > WN - 1 ? WN - 1 : xx);
    }
    float s = 0.0f;
#pragma unroll
    for (int dy = -RAD; dy <= RAD; ++dy) {
        int yy = y + dy;
        yy = yy < 0 ? 0 : (yy > HN - 1 ? HN - 1 : yy);
        const float* row = xb + yy * WN;
#pragma unroll
        for (int k = 0; k < 2 * RAD + 1; ++k) s += row[xs[k]];
    }
    return s;
}

// BM[r-1][b][y][x] = mean of x[clamp(y+dy)][clamp(x+dx)], dy,dx in [-r,r].
// 6 maps x 200 KB = 1.2 MB in d_ws.
__global__ __launch_bounds__(256) void box_mean_direct_kernel(
    const float* __restrict__ x, float* __restrict__ BM)
{
    const int zb = blockIdx.z;                 // r_idx*2 + b
    const int r_idx = zb >> 1, b = zb & 1;
    const int xi = blockIdx.x * 64 + threadIdx.x;   // 0..255 (mask xi<224 on store)
    const int y  = blockIdx.y * 4 + threadIdx.y;
    const int xc = xi < WN ? xi : WN - 1;           // keep masked lanes in-bounds

    const float* xb = x + b * NPIX;
    float s;
    if (r_idx == 0)      s = box_sum<1>(xb, y, xc) * (1.0f / 9.0f);
    else if (r_idx == 1) s = box_sum<2>(xb, y, xc) * (1.0f / 25.0f);
    else                 s = box_sum<3>(xb, y, xc) * (1.0f / 49.0f);

    if (xi < WN)
        BM[(size_t)zb * NPIX + y * WN + xi] = s;
}

// Main v3: coalesced lane->x gathers (v1 pattern, the regression-free one),
// restructured for contiguous output streams + nontemporal stores.
//   - Block (64,4), grid (4, P, B): block = (p, b, 56-row stripe).
//   - Each wave sweeps FULL 224-px rows in 4 chunks of 64 consecutive lanes;
//     the block's 4 waves cover 4 consecutive rows -> the block emits one
//     contiguous ~50 KB output stream (good HBM write locality).
//   - __builtin_nontemporal_store: out (102.8 MB) must not evict the 1.2 MB
//     BM maps from L2 (write-allocate thrash was the suspected hidden cost).
//   - Row bases scalar via readfirstlane; per-chunk column indices hoisted
//     (computed once per block, bit-exact f32 add->clamp->trunc as reference).
__global__ __launch_bounds__(256) void bad_main_kernel(
    const float* __restrict__ BM,
    const float* __restrict__ ox1, const float* __restrict__ ox2,
    const float* __restrict__ oy1, const float* __restrict__ oy2,
    const int*   __restrict__ radii, const float* __restrict__ thr,
    float* __restrict__ out)
{
    const int p    = blockIdx.y;
    const int b    = blockIdx.z;
    const int st   = blockIdx.x;            // 0..3 -> 56-row stripe
    const int lane = threadIdx.x;           // 0..63
    const int wy   = threadIdx.y;           // 0..3, uniform per wave

    // block-uniform descriptor params -> scalar loads
    const float offx1 = ox1[p], offx2 = ox2[p];
    const float offy1 = oy1[p], offy2 = oy2[p];
    const int   rad   = radii[p];
    const float t     = thr[p];

    const float* __restrict__ map = BM + (size_t)((rad - 1) * BN + b) * NPIX;

    // per-lane column indices for all 4 chunks, computed once.
    // Bit-exact with reference: f32 add -> clamp -> trunc.
    int vx1[4], vx2[4];
#pragma unroll
    for (int c = 0; c < 4; ++c) {
        const float fx = (float)(c * 64 + lane);
        vx1[c] = (int)fminf(fmaxf(fx + offx1, 0.0f), (float)(WN - 1));
        vx2[c] = (int)fminf(fmaxf(fx + offx2, 0.0f), (float)(WN - 1));
    }

    const int  y0     = st * (HN / 4) + wy;       // wave-uniform start row
    const bool tailok = (lane < 32);              // chunk 3 covers x=192..223
    float* __restrict__ outp = out + (size_t)(b * PN + p) * NPIX + (size_t)y0 * WN;

#pragma unroll 2
    for (int i = 0; i < HN / 4; i += 4) {
        const float fy = (float)(y0 + i);
        const int cy1 = __builtin_amdgcn_readfirstlane(
                            (int)fminf(fmaxf(fy + offy1, 0.0f), (float)(HN - 1)));
        const int cy2 = __builtin_amdgcn_readfirstlane(
                            (int)fminf(fmaxf(fy + offy2, 0.0f), (float)(HN - 1)));
        const float* __restrict__ r1 = map + cy1 * WN;   // scalar row base
        const float* __restrict__ r2 = map + cy2 * WN;   // scalar row base
        float* __restrict__ orow = outp + (size_t)i * WN;

#pragma unroll
        for (int c = 0; c < 3; ++c) {
            const float v = r1[vx1[c]] - r2[vx2[c]] - t;
            __builtin_nontemporal_store(v, orow + c * 64 + lane);
        }
        const float v3 = r1[vx1[3]] - r2[vx2[3]] - t;
        if (tailok)
            __builtin_nontemporal_store(v3, orow + 192 + lane);
    }
}

extern "C" void kernel_launch(void* const* d_in, const int* in_sizes, int n_in,
                              void* d_out, int out_size, void* d_ws, size_t ws_size,
                              hipStream_t stream)
{
    const float* x    = (const float*)d_in[0];
    const float* ox1  = (const float*)d_in[1];
    const float* ox2  = (const float*)d_in[2];
    const float* oy1  = (const float*)d_in[3];
    const float* oy2  = (const float*)d_in[4];
    const int*   rad  = (const int*)d_in[5];
    const float* thr  = (const float*)d_in[6];

    float* BM  = (float*)d_ws;                // 6 * NPIX floats = ~1.2 MB
    float* out = (float*)d_out;

    hipLaunchKernelGGL(box_mean_direct_kernel, dim3(4, HN / 4, 6), dim3(64, 4, 1), 0, stream, x, BM);
    hipLaunchKernelGGL(bad_main_kernel,        dim3(4, PN, BN),    dim3(64, 4, 1), 0, stream,
                       BM, ox1, ox2, oy1, oy2, rad, thr, out);
}